// Round 4
// baseline (112.117 us; speedup 1.0000x reference)
//
#include <hip/hip_runtime.h>
#include <math.h>

// Problem constants (match reference)
#define BB     32
#define HH     32
#define HKV    8
#define SS     8192
#define DD     128
#define LMAX   1024
#define GQA    (HH / HKV)        // 4
#define NTHR   256
#define NWAVE  4

// Split-L (flash-decoding) parameters
#define CHUNK      128
#define NCHUNK     (LMAX / CHUNK)          // 8
#define RPW        (CHUNK / NWAVE)         // 32 rows per wave
#define WS_STRIDE  (DD + 2)                // floats per partial: m, sum, acc[128]

// ---------------------------------------------------------------------------
// Kernel 1: per-(head, chunk) partial attention, XCD-swizzled so the 4 GQA
// q-heads of one (b,kv) group (32 blocks) land on the SAME XCD -> duplicate
// K/V row gathers become L2 hits (group working set ~1.8 MB < 4 MB L2).
//
// flat f (0..8191):  x = f&7  -> XCD (hw round-robin heuristic) -> kv = x
//                    j = f>>3; b = j>>5; r = j&31; hig = r>>3; c = r&7
// Bijection onto (b, h = kv*4+hig, c).
// ---------------------------------------------------------------------------
__global__ __launch_bounds__(NTHR) void sparse_attn_part(
    const float* __restrict__ q,      // [B,H,1,D]
    const float* __restrict__ K,      // [B,H_KV,S,D]
    const float* __restrict__ V,      // [B,H_KV,S,D]
    const int*   __restrict__ ind,    // [B,H,LMAX]
    const int*   __restrict__ nnz,    // [B,H]
    float*       __restrict__ ws)
{
    const int f   = blockIdx.x;            // 0..8191
    const int kv  = f & 7;                 // XCD-pinned kv head
    const int j   = f >> 3;
    const int b   = j >> 5;
    const int r   = j & 31;
    const int hig = r >> 3;                // head-in-group 0..3
    const int c   = r & 7;                 // chunk 0..7
    const int h   = (kv << 2) + hig;
    const int bh  = (b << 5) + h;

    int L = nnz[bh];
    if (L < 1) L = 1;
    if (L > LMAX) L = LMAX;

    const int start = c * CHUNK;
    if (start >= L) return;                // chunk entirely past nnz
    const int count = min(CHUNK, L - start);

    const int tid  = threadIdx.x;
    const int wave = tid >> 6;
    const int lane = tid & 63;
    const int half = lane >> 5;            // 0 or 1
    const int sub  = lane & 31;            // lane within half

    __shared__ float s_p[CHUNK];           // scores, then p
    __shared__ int   s_ind[CHUNK];
    __shared__ float s_red[NWAVE];
    __shared__ float s_ms[2];              // block m, block sum
    __shared__ float s_acc[NWAVE * 2][DD]; // one partial per half-wave

    const float* __restrict__ Kb = K + (size_t)(b * HKV + kv) * SS * DD;
    const float* __restrict__ Vb = V + (size_t)(b * HKV + kv) * SS * DD;
    const int*   __restrict__ indb = ind + (size_t)bh * LMAX + start;

    if (tid < count) s_ind[tid] = indb[tid];

    // q fragment: each half-wave covers all 128 cols; sub owns cols 4*sub..+3
    const float4 qf = *(const float4*)(q + (size_t)bh * DD + sub * 4);
    const float scale = 0.08838834764831843f;   // 1/sqrt(128)

    __syncthreads();

    // ---- Phase 1: scores (2 rows per wave-iteration) --------------------
    const int wbeg = wave * RPW;
    const int wend = min(wbeg + RPW, count);
    #pragma unroll 4
    for (int l = wbeg + half; l < wend; l += 2) {
        const int row = s_ind[l];
        const float4 kf = *(const float4*)(Kb + (size_t)row * DD + sub * 4);
        float partial = kf.x * qf.x + kf.y * qf.y + kf.z * qf.z + kf.w * qf.w;
        #pragma unroll
        for (int off = 16; off >= 1; off >>= 1)
            partial += __shfl_xor(partial, off, 64);   // stays within half
        if (sub == 0) s_p[l] = partial * scale;
    }
    __syncthreads();

    // ---- block max ------------------------------------------------------
    float m = (tid < count) ? s_p[tid] : -INFINITY;
    #pragma unroll
    for (int off = 32; off >= 1; off >>= 1)
        m = fmaxf(m, __shfl_xor(m, off, 64));
    if (lane == 0) s_red[wave] = m;
    __syncthreads();
    m = fmaxf(fmaxf(s_red[0], s_red[1]), fmaxf(s_red[2], s_red[3]));
    __syncthreads();

    // ---- exp + sum ------------------------------------------------------
    float sum = 0.f;
    if (tid < count) {
        const float p = __expf(s_p[tid] - m);
        s_p[tid] = p;
        sum = p;
    }
    #pragma unroll
    for (int off = 32; off >= 1; off >>= 1)
        sum += __shfl_xor(sum, off, 64);
    if (lane == 0) s_red[wave] = sum;
    __syncthreads();
    if (tid == 0) {
        s_ms[0] = m;
        s_ms[1] = s_red[0] + s_red[1] + s_red[2] + s_red[3];
    }

    // ---- Phase 2: acc += p[l] * V[row_l] (2 rows per iteration) ---------
    float4 acc = make_float4(0.f, 0.f, 0.f, 0.f);
    #pragma unroll 4
    for (int l = wbeg + half; l < wend; l += 2) {
        const int row = s_ind[l];
        const float p = s_p[l];
        const float4 vf = *(const float4*)(Vb + (size_t)row * DD + sub * 4);
        acc.x = fmaf(p, vf.x, acc.x);
        acc.y = fmaf(p, vf.y, acc.y);
        acc.z = fmaf(p, vf.z, acc.z);
        acc.w = fmaf(p, vf.w, acc.w);
    }
    *(float4*)&s_acc[wave * 2 + half][sub * 4] = acc;
    __syncthreads();

    float* __restrict__ wsp = ws + ((size_t)bh * NCHUNK + c) * WS_STRIDE;
    if (tid < DD) {
        float rsum = 0.f;
        #pragma unroll
        for (int i = 0; i < NWAVE * 2; ++i) rsum += s_acc[i][tid];
        wsp[2 + tid] = rsum;
    } else if (tid == DD) {
        wsp[0] = s_ms[0];
    } else if (tid == DD + 1) {
        wsp[1] = s_ms[1];
    }
}

// ---------------------------------------------------------------------------
// Kernel 2: combine partials with split-softmax rescaling.
// ---------------------------------------------------------------------------
__global__ __launch_bounds__(DD) void sparse_attn_combine(
    const int*   __restrict__ nnz,
    const float* __restrict__ ws,
    float*       __restrict__ out)    // [B,H,1,D]
{
    const int bh = blockIdx.x;
    const int t  = threadIdx.x;       // 0..127

    int L = nnz[bh];
    if (L < 1) L = 1;
    if (L > LMAX) L = LMAX;
    const int nc = (L + CHUNK - 1) / CHUNK;

    const float* __restrict__ base = ws + (size_t)bh * NCHUNK * WS_STRIDE;

    float M = -INFINITY;
    for (int cidx = 0; cidx < nc; ++cidx)
        M = fmaxf(M, base[cidx * WS_STRIDE]);

    float denom = 0.f, acc = 0.f;
    for (int cidx = 0; cidx < nc; ++cidx) {
        const float w = __expf(base[cidx * WS_STRIDE] - M);
        denom = fmaf(base[cidx * WS_STRIDE + 1], w, denom);
        acc   = fmaf(base[cidx * WS_STRIDE + 2 + t], w, acc);
    }
    out[(size_t)bh * DD + t] = acc / denom;
}

// ---------------------------------------------------------------------------
// Fallback: single-kernel version if ws is too small (never expected).
// ---------------------------------------------------------------------------
__global__ __launch_bounds__(NTHR) void sparse_attn_single(
    const float* __restrict__ q, const float* __restrict__ K,
    const float* __restrict__ V, const int* __restrict__ ind,
    const int* __restrict__ nnz, float* __restrict__ out)
{
    const int bh   = blockIdx.x;
    const int b    = bh / HH;
    const int h    = bh - b * HH;
    const int kv   = h / GQA;
    const int tid  = threadIdx.x;
    const int wave = tid >> 6;
    const int lane = tid & 63;

    __shared__ float s_scores[LMAX];
    __shared__ int   s_ind[LMAX];
    __shared__ float s_red[NWAVE];
    __shared__ float s_acc[NWAVE][DD];

    const float* __restrict__ Kb = K + (size_t)(b * HKV + kv) * SS * DD;
    const float* __restrict__ Vb = V + (size_t)(b * HKV + kv) * SS * DD;
    const int*   __restrict__ indb = ind + (size_t)bh * LMAX;

    int L = nnz[bh];
    if (L < 1) L = 1;
    if (L > LMAX) L = LMAX;

    for (int l = tid; l < L; l += NTHR) s_ind[l] = indb[l];
    const float2 qf = *(const float2*)(q + (size_t)bh * DD + lane * 2);
    const float scale = 0.08838834764831843f;
    __syncthreads();

    #pragma unroll 2
    for (int l = wave; l < L; l += NWAVE) {
        const int row = s_ind[l];
        const float2 kf = *(const float2*)(Kb + (size_t)row * DD + lane * 2);
        float partial = kf.x * qf.x + kf.y * qf.y;
        #pragma unroll
        for (int off = 32; off >= 1; off >>= 1)
            partial += __shfl_xor(partial, off, 64);
        if (lane == 0) s_scores[l] = partial * scale;
    }
    __syncthreads();

    float m = -INFINITY;
    for (int l = tid; l < L; l += NTHR) m = fmaxf(m, s_scores[l]);
    #pragma unroll
    for (int off = 32; off >= 1; off >>= 1)
        m = fmaxf(m, __shfl_xor(m, off, 64));
    if (lane == 0) s_red[wave] = m;
    __syncthreads();
    m = fmaxf(fmaxf(s_red[0], s_red[1]), fmaxf(s_red[2], s_red[3]));
    __syncthreads();

    float sum = 0.f;
    for (int l = tid; l < L; l += NTHR) {
        const float p = __expf(s_scores[l] - m);
        s_scores[l] = p;
        sum += p;
    }
    #pragma unroll
    for (int off = 32; off >= 1; off >>= 1)
        sum += __shfl_xor(sum, off, 64);
    if (lane == 0) s_red[wave] = sum;
    __syncthreads();
    const float inv_denom = 1.0f / (s_red[0] + s_red[1] + s_red[2] + s_red[3]);

    float accx = 0.f, accy = 0.f;
    #pragma unroll 2
    for (int l = wave; l < L; l += NWAVE) {
        const int row = s_ind[l];
        const float p = s_scores[l];
        const float2 vf = *(const float2*)(Vb + (size_t)row * DD + lane * 2);
        accx = fmaf(p, vf.x, accx);
        accy = fmaf(p, vf.y, accy);
    }
    s_acc[wave][lane * 2]     = accx;
    s_acc[wave][lane * 2 + 1] = accy;
    __syncthreads();

    if (tid < DD) {
        const float r = s_acc[0][tid] + s_acc[1][tid] + s_acc[2][tid] + s_acc[3][tid];
        out[(size_t)bh * DD + tid] = r * inv_denom;
    }
}

extern "C" void kernel_launch(void* const* d_in, const int* in_sizes, int n_in,
                              void* d_out, int out_size, void* d_ws, size_t ws_size,
                              hipStream_t stream) {
    const float* q   = (const float*)d_in[0];
    const float* K   = (const float*)d_in[1];
    const float* V   = (const float*)d_in[2];
    const int*   ind = (const int*)d_in[3];
    const int*   nnz = (const int*)d_in[4];
    float* out = (float*)d_out;

    const size_t ws_needed = (size_t)BB * HH * NCHUNK * WS_STRIDE * sizeof(float);
    if (ws_size >= ws_needed) {
        float* ws = (float*)d_ws;
        sparse_attn_part<<<BB * HH * NCHUNK, NTHR, 0, stream>>>(q, K, V, ind, nnz, ws);
        sparse_attn_combine<<<BB * HH, DD, 0, stream>>>(nnz, ws, out);
    } else {
        sparse_attn_single<<<BB * HH, NTHR, 0, stream>>>(q, K, V, ind, nnz, out);
    }
}

// Round 5
// 102.285 us; speedup vs baseline: 1.0961x; 1.0961x over previous
//
#include <hip/hip_runtime.h>
#include <math.h>

// Problem constants (match reference)
#define BB     32
#define HH     32
#define HKV    8
#define SS     8192
#define DD     128
#define LMAX   1024
#define GQA    (HH / HKV)        // 4
#define NTHR   256
#define NWAVE  4

// Split-L (flash-decoding) parameters
#define CHUNK      128
#define NCHUNK     (LMAX / CHUNK)          // 8
#define RPW        (CHUNK / NWAVE)         // 32 rows per wave (16 per half-wave)
#define WS_STRIDE  (DD + 2)                // floats per partial: m, sum, acc[128]
#define NHW        (NWAVE * 2)             // 8 half-waves

// ---------------------------------------------------------------------------
// Kernel 1: per-(head, chunk) partial attention, FUSED single pass.
// Each half-wave (32 lanes) runs an online softmax over its 16 rows:
// K-row and V-row loads issue together (2x MLP), score reduced with 5
// intra-half shfl_xor, rescale only on new max (half-wave-uniform branch).
// 8 half-wave partials combine in-block; one (m,sum,acc[128]) per chunk to ws.
// ---------------------------------------------------------------------------
__global__ __launch_bounds__(NTHR) void sparse_attn_part(
    const float* __restrict__ q,      // [B,H,1,D]
    const float* __restrict__ K,      // [B,H_KV,S,D]
    const float* __restrict__ V,      // [B,H_KV,S,D]
    const int*   __restrict__ ind,    // [B,H,LMAX]
    const int*   __restrict__ nnz,    // [B,H]
    float*       __restrict__ ws)
{
    const int bh = blockIdx.x;             // 0..B*H-1
    const int c  = blockIdx.y;             // 0..NCHUNK-1

    int L = nnz[bh];
    if (L < 1) L = 1;
    if (L > LMAX) L = LMAX;

    const int start = c * CHUNK;
    if (start >= L) return;                // chunk entirely past nnz
    const int count = min(CHUNK, L - start);

    const int b    = bh / HH;
    const int h    = bh - b * HH;
    const int kv   = h / GQA;
    const int tid  = threadIdx.x;
    const int wave = tid >> 6;
    const int lane = tid & 63;
    const int half = lane >> 5;            // 0 or 1
    const int sub  = lane & 31;            // lane within half
    const int hw   = wave * 2 + half;      // 0..7

    __shared__ int   s_ind[CHUNK];
    __shared__ float s_m[NHW];
    __shared__ float s_sum[NHW];
    __shared__ float s_acc[NHW][DD];

    const float* __restrict__ Kb = K + (size_t)(b * HKV + kv) * SS * DD;
    const float* __restrict__ Vb = V + (size_t)(b * HKV + kv) * SS * DD;
    const int*   __restrict__ indb = ind + (size_t)bh * LMAX + start;

    if (tid < count) s_ind[tid] = indb[tid];

    // q fragment: each half-wave covers all 128 cols; sub owns cols 4*sub..+3
    const float4 qf = *(const float4*)(q + (size_t)bh * DD + sub * 4);
    const float scale = 0.08838834764831843f;   // 1/sqrt(128)

    __syncthreads();

    // ---- fused online pass over this half-wave's rows -------------------
    float  m   = -INFINITY;
    float  sum = 0.f;
    float4 acc = make_float4(0.f, 0.f, 0.f, 0.f);

    const int wbeg = wave * RPW;
    const int wend = min(wbeg + RPW, count);
    #pragma unroll 4
    for (int l = wbeg + half; l < wend; l += 2) {
        const int row = s_ind[l];
        const float4 kf = *(const float4*)(Kb + (size_t)row * DD + sub * 4);
        const float4 vf = *(const float4*)(Vb + (size_t)row * DD + sub * 4);
        float s = kf.x * qf.x + kf.y * qf.y + kf.z * qf.z + kf.w * qf.w;
        #pragma unroll
        for (int off = 16; off >= 1; off >>= 1)
            s += __shfl_xor(s, off, 64);   // stays within the 32-lane half
        s *= scale;
        if (s > m) {                       // half-wave-uniform branch
            const float corr = __expf(m - s);  // first iter: exp(-inf)=0
            acc.x *= corr; acc.y *= corr; acc.z *= corr; acc.w *= corr;
            sum *= corr;
            m = s;
        }
        const float w = __expf(s - m);
        acc.x = fmaf(w, vf.x, acc.x);
        acc.y = fmaf(w, vf.y, acc.y);
        acc.z = fmaf(w, vf.z, acc.z);
        acc.w = fmaf(w, vf.w, acc.w);
        sum += w;
    }

    if (sub == 0) { s_m[hw] = m; s_sum[hw] = sum; }
    *(float4*)&s_acc[hw][sub * 4] = acc;
    __syncthreads();

    // ---- combine 8 half-wave partials -> one chunk partial --------------
    float* __restrict__ wsp = ws + ((size_t)bh * NCHUNK + c) * WS_STRIDE;
    if (tid < DD) {
        float M = s_m[0];
        #pragma unroll
        for (int i = 1; i < NHW; ++i) M = fmaxf(M, s_m[i]);
        float denom = 0.f, r = 0.f;
        #pragma unroll
        for (int i = 0; i < NHW; ++i) {
            const float wgt = __expf(s_m[i] - M);   // -inf partials -> 0
            denom = fmaf(wgt, s_sum[i], denom);
            r     = fmaf(wgt, s_acc[i][tid], r);
        }
        wsp[2 + tid] = r;
        if (tid == 0) { wsp[0] = M; wsp[1] = denom; }
    }
}

// ---------------------------------------------------------------------------
// Kernel 2: combine chunk partials with split-softmax rescaling.
// ---------------------------------------------------------------------------
__global__ __launch_bounds__(DD) void sparse_attn_combine(
    const int*   __restrict__ nnz,
    const float* __restrict__ ws,
    float*       __restrict__ out)    // [B,H,1,D]
{
    const int bh = blockIdx.x;
    const int t  = threadIdx.x;       // 0..127

    int L = nnz[bh];
    if (L < 1) L = 1;
    if (L > LMAX) L = LMAX;
    const int nc = (L + CHUNK - 1) / CHUNK;

    const float* __restrict__ base = ws + (size_t)bh * NCHUNK * WS_STRIDE;

    float M = -INFINITY;
    for (int cidx = 0; cidx < nc; ++cidx)
        M = fmaxf(M, base[cidx * WS_STRIDE]);

    float denom = 0.f, acc = 0.f;
    for (int cidx = 0; cidx < nc; ++cidx) {
        const float w = __expf(base[cidx * WS_STRIDE] - M);
        denom = fmaf(base[cidx * WS_STRIDE + 1], w, denom);
        acc   = fmaf(base[cidx * WS_STRIDE + 2 + t], w, acc);
    }
    out[(size_t)bh * DD + t] = acc / denom;
}

// ---------------------------------------------------------------------------
// Fallback: single-kernel version if ws is too small (never expected).
// ---------------------------------------------------------------------------
__global__ __launch_bounds__(NTHR) void sparse_attn_single(
    const float* __restrict__ q, const float* __restrict__ K,
    const float* __restrict__ V, const int* __restrict__ ind,
    const int* __restrict__ nnz, float* __restrict__ out)
{
    const int bh   = blockIdx.x;
    const int b    = bh / HH;
    const int h    = bh - b * HH;
    const int kv   = h / GQA;
    const int tid  = threadIdx.x;
    const int wave = tid >> 6;
    const int lane = tid & 63;

    __shared__ float s_scores[LMAX];
    __shared__ int   s_ind[LMAX];
    __shared__ float s_red[NWAVE];
    __shared__ float s_acc[NWAVE][DD];

    const float* __restrict__ Kb = K + (size_t)(b * HKV + kv) * SS * DD;
    const float* __restrict__ Vb = V + (size_t)(b * HKV + kv) * SS * DD;
    const int*   __restrict__ indb = ind + (size_t)bh * LMAX;

    int L = nnz[bh];
    if (L < 1) L = 1;
    if (L > LMAX) L = LMAX;

    for (int l = tid; l < L; l += NTHR) s_ind[l] = indb[l];
    const float2 qf = *(const float2*)(q + (size_t)bh * DD + lane * 2);
    const float scale = 0.08838834764831843f;
    __syncthreads();

    #pragma unroll 2
    for (int l = wave; l < L; l += NWAVE) {
        const int row = s_ind[l];
        const float2 kf = *(const float2*)(Kb + (size_t)row * DD + lane * 2);
        float partial = kf.x * qf.x + kf.y * qf.y;
        #pragma unroll
        for (int off = 32; off >= 1; off >>= 1)
            partial += __shfl_xor(partial, off, 64);
        if (lane == 0) s_scores[l] = partial * scale;
    }
    __syncthreads();

    float m = -INFINITY;
    for (int l = tid; l < L; l += NTHR) m = fmaxf(m, s_scores[l]);
    #pragma unroll
    for (int off = 32; off >= 1; off >>= 1)
        m = fmaxf(m, __shfl_xor(m, off, 64));
    if (lane == 0) s_red[wave] = m;
    __syncthreads();
    m = fmaxf(fmaxf(s_red[0], s_red[1]), fmaxf(s_red[2], s_red[3]));
    __syncthreads();

    float sum = 0.f;
    for (int l = tid; l < L; l += NTHR) {
        const float p = __expf(s_scores[l] - m);
        s_scores[l] = p;
        sum += p;
    }
    #pragma unroll
    for (int off = 32; off >= 1; off >>= 1)
        sum += __shfl_xor(sum, off, 64);
    if (lane == 0) s_red[wave] = sum;
    __syncthreads();
    const float inv_denom = 1.0f / (s_red[0] + s_red[1] + s_red[2] + s_red[3]);

    float accx = 0.f, accy = 0.f;
    #pragma unroll 2
    for (int l = wave; l < L; l += NWAVE) {
        const int row = s_ind[l];
        const float p = s_scores[l];
        const float2 vf = *(const float2*)(Vb + (size_t)row * DD + lane * 2);
        accx = fmaf(p, vf.x, accx);
        accy = fmaf(p, vf.y, accy);
    }
    s_acc[wave][lane * 2]     = accx;
    s_acc[wave][lane * 2 + 1] = accy;
    __syncthreads();

    if (tid < DD) {
        const float r = s_acc[0][tid] + s_acc[1][tid] + s_acc[2][tid] + s_acc[3][tid];
        out[(size_t)bh * DD + tid] = r * inv_denom;
    }
}

extern "C" void kernel_launch(void* const* d_in, const int* in_sizes, int n_in,
                              void* d_out, int out_size, void* d_ws, size_t ws_size,
                              hipStream_t stream) {
    const float* q   = (const float*)d_in[0];
    const float* K   = (const float*)d_in[1];
    const float* V   = (const float*)d_in[2];
    const int*   ind = (const int*)d_in[3];
    const int*   nnz = (const int*)d_in[4];
    float* out = (float*)d_out;

    const size_t ws_needed = (size_t)BB * HH * NCHUNK * WS_STRIDE * sizeof(float);
    if (ws_size >= ws_needed) {
        float* ws = (float*)d_ws;
        dim3 grid1(BB * HH, NCHUNK);
        sparse_attn_part<<<grid1, NTHR, 0, stream>>>(q, K, V, ind, nnz, ws);
        sparse_attn_combine<<<BB * HH, DD, 0, stream>>>(nnz, ws, out);
    } else {
        sparse_attn_single<<<BB * HH, NTHR, 0, stream>>>(q, K, V, ind, nnz, out);
    }
}